// Round 3
// baseline (711.996 us; speedup 1.0000x reference)
//
#include <hip/hip_runtime.h>

// Problem constants: BS=4, T=2048, H=512, NH=8, DH=64, Nqkv=1088, M=8192
typedef unsigned short u16;
typedef __bf16 bf16x8 __attribute__((ext_vector_type(8)));
typedef short s16x4 __attribute__((ext_vector_type(4)));
typedef float f32x4 __attribute__((ext_vector_type(4)));
static_assert(sizeof(bf16x8) == 16, "bf16x8 must be 16B");

#define MFMA32(a, b, c) __builtin_amdgcn_mfma_f32_16x16x32_bf16(a, b, c, 0, 0, 0)
#define MFMA16(a, b, c) __builtin_amdgcn_mfma_f32_16x16x16bf16_1k(a, b, c, 0, 0, 0)

__device__ __forceinline__ u16 f2bf(float f) {
  unsigned u = __float_as_uint(f);
  u += 0x7fffu + ((u >> 16) & 1u);  // RNE; inputs finite
  return (u16)(u >> 16);
}

// ---------------------------------------------------------------------------
// prep: x->bf16 xh[8192][512]; w_qkv -> wt[1088 n][512 k] bf16 (Q cols
// pre-scaled by 0.125, exact pow2); w_out -> wot[512 n][64 k] bf16.
// ---------------------------------------------------------------------------
__global__ __launch_bounds__(256) void prep_kernel(
    const float* __restrict__ x, const float* __restrict__ wqkv,
    const float* __restrict__ wout, u16* __restrict__ xh,
    u16* __restrict__ wt, u16* __restrict__ wot) {
  int blk = blockIdx.x, tid = threadIdx.x;
  if (blk < 4096) {
    int idx = (blk * 256 + tid) * 4;
    float4 v = *(const float4*)(x + idx);
    ushort4 o;
    o.x = f2bf(v.x); o.y = f2bf(v.y); o.z = f2bf(v.z); o.w = f2bf(v.w);
    *(ushort4*)(xh + idx) = o;
  } else if (blk < 4096 + 2176) {
    int idx = (blk - 4096) * 256 + tid;
    int n = idx >> 9, k = idx & 511;
    float v = wqkv[k * 1088 + n];
    if (n < 512) v *= 0.125f;
    wt[idx] = f2bf(v);
  } else {
    int idx = (blk - 6272) * 256 + tid;
    int n = idx >> 6, d = idx & 63;
    wot[idx] = f2bf(wout[d * 512 + n]);
  }
}

// ---------------------------------------------------------------------------
// QKV GEMM: 128x64 tile, BK=32, register-prefetch pipeline. Scatter to
//   Qb [bh][t][d] (scaled), Kb [bh][t][d], Vt [b][d][t]
// ---------------------------------------------------------------------------
__global__ __launch_bounds__(256) void qkv_gemm_kernel(
    const u16* __restrict__ xh, const u16* __restrict__ wt,
    u16* __restrict__ Qb, u16* __restrict__ Kb, u16* __restrict__ Vt) {
  __shared__ u16 As[128][40];  // [m][k] pad 8
  __shared__ u16 Bs[64][40];   // [n][k] pad 8
  const int tid = threadIdx.x;
  const int w = tid >> 6, l = tid & 63, g = l >> 4, c16 = l & 15;
  const int n0 = blockIdx.x * 64;    // 17 blocks
  const int m0 = blockIdx.y * 128;   // 64 blocks
  const int arow = tid >> 1, acol = (tid & 1) << 4;  // A: 128x32, 2 uint4/thr
  const int brow = tid >> 2, bcol = (tid & 3) << 3;  // B: 64x32, 1 uint4/thr
  const u16* ap = xh + (size_t)(m0 + arow) * 512 + acol;
  const u16* bp = wt + (size_t)(n0 + brow) * 512 + bcol;
  uint4 pa0 = *(const uint4*)(ap);
  uint4 pa1 = *(const uint4*)(ap + 8);
  uint4 pb0 = *(const uint4*)(bp);
  f32x4 acc[2][4] = {};
  for (int k0 = 0; k0 < 512; k0 += 32) {
    __syncthreads();
    *(uint4*)&As[arow][acol] = pa0;
    *(uint4*)&As[arow][acol + 8] = pa1;
    *(uint4*)&Bs[brow][bcol] = pb0;
    __syncthreads();
    if (k0 + 32 < 512) {  // prefetch overlaps with compute below
      pa0 = *(const uint4*)(ap + k0 + 32);
      pa1 = *(const uint4*)(ap + k0 + 40);
      pb0 = *(const uint4*)(bp + k0 + 32);
    }
#pragma unroll
    for (int mt = 0; mt < 2; ++mt) {
      bf16x8 a = *(const bf16x8*)&As[w * 32 + mt * 16 + c16][g * 8];
#pragma unroll
      for (int nt = 0; nt < 4; ++nt) {
        bf16x8 b = *(const bf16x8*)&Bs[nt * 16 + c16][g * 8];
        acc[mt][nt] = MFMA32(a, b, acc[mt][nt]);
      }
    }
  }
#pragma unroll
  for (int mt = 0; mt < 2; ++mt)
#pragma unroll
    for (int nt = 0; nt < 4; ++nt)
#pragma unroll
      for (int j = 0; j < 4; ++j) {
        u16 bv = f2bf(acc[mt][nt][j]);
        int row = m0 + w * 32 + mt * 16 + g * 4 + j;  // b*2048+t
        int b = row >> 11, t = row & 2047;
        int col = n0 + nt * 16 + c16;
        if (col < 512) {
          int h = col >> 6, d = col & 63;
          Qb[((size_t)((b << 3) + h) * 2048 + t) * 64 + d] = bv;
        } else if (col < 1024) {
          int cc = col - 512, h = cc >> 6, d = cc & 63;
          Kb[((size_t)((b << 3) + h) * 2048 + t) * 64 + d] = bv;
        } else {
          int d = col - 1024;
          Vt[((size_t)((b << 6) + d)) * 2048 + t] = bv;
        }
      }
}

// ---------------------------------------------------------------------------
// Attention, S-TRANSPOSED formulation. Per block: (bh, 64-row q-tile).
// S^T = MFMA(A=K rows, B=Q rows): C/D frag holds (k=quad*4+reg, q=lane&15).
//  -> P global store is float4-contiguous in k.
//  -> frag doubles as the A-operand of mfma_f32_16x16x16bf16_1k (m=lane&15,
//     k=quad*4+i): NO transpose/LDS round-trip for PV.
// Waves partition k (16 rows each); partial O reduced across waves in LDS
// once at the end. No max-subtraction (scores ~N(0,1), fp32 exp safe).
// ---------------------------------------------------------------------------
__global__ __launch_bounds__(256) void attn_kernel(
    const u16* __restrict__ Qb, const u16* __restrict__ Kb,
    const u16* __restrict__ Vt, float* __restrict__ P,
    float* __restrict__ Obuf) {
  __shared__ __align__(16) char smem[27648];   // Qs | Ks | Vs (64x72 u16 each)
  __shared__ float Lred[256];                  // per-wave row-sum partials
  u16 (*Qs)[72] = (u16(*)[72])smem;
  u16 (*Ks)[72] = (u16(*)[72])(smem + 9216);
  u16 (*Vs)[72] = (u16(*)[72])(smem + 18432);
  float* Osum = (float*)smem;  // 64x68 fp32 = 17408B, aliases Qs+Ks (dead)

  const int tid = threadIdx.x;
  const int w = tid >> 6, l = tid & 63, g = l >> 4, c16 = l & 15;
  const int qt = blockIdx.x & 31, bh = blockIdx.x >> 5, b = bh >> 3;
  const int srow = tid >> 2, scol = (tid & 3) << 4;
  const int kl = w * 16 + g * 4;  // lane's k-row base within the 64-k tile

  {  // stage Q
    const u16* src = Qb + ((size_t)(bh * 2048 + qt * 64 + srow)) * 64 + scol;
    *(uint4*)&Qs[srow][scol] = *(const uint4*)src;
    *(uint4*)&Qs[srow][scol + 8] = *(const uint4*)(src + 8);
  }
  __syncthreads();
  bf16x8 bq[4][2];  // Q as B-operand, loop-invariant, all 4 q-chunks
#pragma unroll
  for (int nt = 0; nt < 4; ++nt) {
    bq[nt][0] = *(const bf16x8*)&Qs[nt * 16 + c16][g * 8];
    bq[nt][1] = *(const bf16x8*)&Qs[nt * 16 + c16][32 + g * 8];
  }

  const u16* kbase = Kb + (size_t)bh * 2048 * 64;
  const u16* vbase = Vt + (size_t)(b << 6) * 2048;

  // -------- pass 1: row sums of exp(s) --------
  float lsum[4] = {0.f, 0.f, 0.f, 0.f};
  uint4 ka0 = *(const uint4*)(kbase + (size_t)srow * 64 + scol);
  uint4 ka1 = *(const uint4*)(kbase + (size_t)srow * 64 + scol + 8);
  for (int kt = 0; kt <= qt; ++kt) {
    __syncthreads();
    *(uint4*)&Ks[srow][scol] = ka0;
    *(uint4*)&Ks[srow][scol + 8] = ka1;
    __syncthreads();
    if (kt < qt) {
      const u16* kn = kbase + (size_t)((kt + 1) * 64 + srow) * 64 + scol;
      ka0 = *(const uint4*)kn;
      ka1 = *(const uint4*)(kn + 8);
    }
    bf16x8 ak0 = *(const bf16x8*)&Ks[w * 16 + c16][g * 8];
    bf16x8 ak1 = *(const bf16x8*)&Ks[w * 16 + c16][32 + g * 8];
#pragma unroll
    for (int nt = 0; nt < 4; ++nt) {
      f32x4 s = {};
      s = MFMA32(ak0, bq[nt][0], s);
      s = MFMA32(ak1, bq[nt][1], s);
      const int qcol = nt * 16 + c16;
      if (kt == qt) {
#pragma unroll
        for (int j = 0; j < 4; ++j)
          lsum[nt] += (kl + j > qcol) ? 0.0f : __expf(s[j]);
      } else {
#pragma unroll
        for (int j = 0; j < 4; ++j) lsum[nt] += __expf(s[j]);
      }
    }
  }
  // reduce over quads (k within wave), then waves via LDS
#pragma unroll
  for (int nt = 0; nt < 4; ++nt) {
    lsum[nt] += __shfl_xor(lsum[nt], 16, 64);
    lsum[nt] += __shfl_xor(lsum[nt], 32, 64);
  }
  if (g == 0) {
#pragma unroll
    for (int nt = 0; nt < 4; ++nt) Lred[w * 64 + nt * 16 + c16] = lsum[nt];
  }
  __syncthreads();
  float rl[4];
#pragma unroll
  for (int nt = 0; nt < 4; ++nt) {
    int q = nt * 16 + c16;
    rl[nt] = 1.0f / (Lred[q] + Lred[64 + q] + Lred[128 + q] + Lred[192 + q]);
  }

  // -------- pass 2: P write + PV (k-partitioned partial O) --------
  f32x4 oacc[4][4] = {};  // [q-chunk][d-chunk], partial over wave's k rows
  ka0 = *(const uint4*)(kbase + (size_t)srow * 64 + scol);
  ka1 = *(const uint4*)(kbase + (size_t)srow * 64 + scol + 8);
  uint4 va0 = *(const uint4*)(vbase + (size_t)srow * 2048 + scol);
  uint4 va1 = *(const uint4*)(vbase + (size_t)srow * 2048 + scol + 8);
  for (int kt = 0; kt <= qt; ++kt) {
    __syncthreads();
    *(uint4*)&Ks[srow][scol] = ka0;
    *(uint4*)&Ks[srow][scol + 8] = ka1;
    *(uint4*)&Vs[srow][scol] = va0;
    *(uint4*)&Vs[srow][scol + 8] = va1;
    __syncthreads();
    if (kt < qt) {
      const u16* kn = kbase + (size_t)((kt + 1) * 64 + srow) * 64 + scol;
      ka0 = *(const uint4*)kn;
      ka1 = *(const uint4*)(kn + 8);
      const u16* vn = vbase + (size_t)srow * 2048 + (kt + 1) * 64 + scol;
      va0 = *(const uint4*)vn;
      va1 = *(const uint4*)(vn + 8);
    }
    bf16x8 ak0 = *(const bf16x8*)&Ks[w * 16 + c16][g * 8];
    bf16x8 ak1 = *(const bf16x8*)&Ks[w * 16 + c16][32 + g * 8];
    s16x4 bv[4];  // V B-frags for the wave's 16-k window, 4 d-chunks
#pragma unroll
    for (int dc = 0; dc < 4; ++dc)
      bv[dc] = *(const s16x4*)&Vs[dc * 16 + c16][kl];
    float* pb = P + ((size_t)(bh * 2048 + qt * 64)) * 2048 + (size_t)kt * 64 + kl;
#pragma unroll
    for (int nt = 0; nt < 4; ++nt) {
      f32x4 s = {};
      s = MFMA32(ak0, bq[nt][0], s);
      s = MFMA32(ak1, bq[nt][1], s);
      const int qcol = nt * 16 + c16;
      float p0 = __expf(s[0]) * rl[nt], p1 = __expf(s[1]) * rl[nt];
      float p2 = __expf(s[2]) * rl[nt], p3 = __expf(s[3]) * rl[nt];
      if (kt == qt) {  // causal mask on the diagonal tile
        p0 = (kl + 0 > qcol) ? 0.f : p0;
        p1 = (kl + 1 > qcol) ? 0.f : p1;
        p2 = (kl + 2 > qcol) ? 0.f : p2;
        p3 = (kl + 3 > qcol) ? 0.f : p3;
      }
      f32x4 pv = {p0, p1, p2, p3};
      __builtin_nontemporal_store(pv, (f32x4*)(pb + (size_t)qcol * 2048));
      s16x4 ap = {(short)f2bf(p0), (short)f2bf(p1),
                  (short)f2bf(p2), (short)f2bf(p3)};  // == A-frag, K=16
#pragma unroll
      for (int dc = 0; dc < 4; ++dc)
        oacc[nt][dc] = MFMA16(ap, bv[dc], oacc[nt][dc]);
    }
  }

  // cross-wave O reduction in LDS (Qs/Ks region dead after last frag reads)
  __syncthreads();
  for (int i = tid; i < 64 * 68; i += 256) Osum[i] = 0.0f;
  __syncthreads();
#pragma unroll
  for (int nt = 0; nt < 4; ++nt)
#pragma unroll
    for (int dc = 0; dc < 4; ++dc)
#pragma unroll
      for (int j = 0; j < 4; ++j)
        atomicAdd(&Osum[(nt * 16 + g * 4 + j) * 68 + dc * 16 + c16],
                  oacc[nt][dc][j]);
  __syncthreads();
  {  // store O tile (fp32) for mean+projection
    float* ob = Obuf + ((size_t)(bh * 2048 + qt * 64 + srow)) * 64;
    const int oc = (tid & 3) << 4;
#pragma unroll
    for (int q4 = 0; q4 < 4; ++q4)
      *(f32x4*)(ob + oc + q4 * 4) = *(const f32x4*)&Osum[srow * 68 + oc + q4 * 4];
  }
  {  // zero-fill strictly-upper k-region (nontemporal)
    int colstart = (qt + 1) * 64;
    int nf4 = (2048 - colstart) >> 2;
    float* base = P + ((size_t)(bh * 2048 + qt * 64)) * 2048;
    f32x4 z = {0.f, 0.f, 0.f, 0.f};
    for (int r = 0; r < 64; ++r) {
      f32x4* rowp = (f32x4*)(base + (size_t)r * 2048 + colstart);
      for (int u = tid; u < nf4; u += 256)
        __builtin_nontemporal_store(z, rowp + u);
    }
  }
}

// ---------------------------------------------------------------------------
// mean over heads: Obuf [bh][t][64] fp32 -> meanb [8192][64] bf16 (x 1/8)
// ---------------------------------------------------------------------------
__global__ __launch_bounds__(256) void mean_kernel(
    const float* __restrict__ Obuf, u16* __restrict__ meanb) {
  int o4 = blockIdx.x * 256 + threadIdx.x;  // 131072 float4 outputs
  int d4 = o4 & 15, t = (o4 >> 4) & 2047, b = o4 >> 15;
  f32x4 acc = {0.f, 0.f, 0.f, 0.f};
#pragma unroll
  for (int h = 0; h < 8; ++h) {
    f32x4 v = *(const f32x4*)(Obuf +
        ((size_t)((b << 3) + h) * 2048 + t) * 64 + d4 * 4);
    acc += v;
  }
  ushort4 o;
  o.x = f2bf(acc[0] * 0.125f); o.y = f2bf(acc[1] * 0.125f);
  o.z = f2bf(acc[2] * 0.125f); o.w = f2bf(acc[3] * 0.125f);
  *(ushort4*)(meanb + (size_t)o4 * 4) = o;
}

// ---------------------------------------------------------------------------
// out = meanb @ w_out : M=8192, N=512, K=64
// ---------------------------------------------------------------------------
__global__ __launch_bounds__(256) void out_gemm_kernel(
    const u16* __restrict__ meanb, const u16* __restrict__ wot,
    float* __restrict__ out) {
  __shared__ u16 As[64][72];
  __shared__ u16 Bs[64][72];
  const int tid = threadIdx.x;
  const int w = tid >> 6, l = tid & 63, g = l >> 4, c16 = l & 15;
  const int n0 = blockIdx.x * 64;
  const int m0 = blockIdx.y * 64;
  const int srow = tid >> 2, scol = (tid & 3) << 4;
  {
    const u16* asrc = meanb + (size_t)(m0 + srow) * 64 + scol;
    *(uint4*)&As[srow][scol] = *(const uint4*)(asrc);
    *(uint4*)&As[srow][scol + 8] = *(const uint4*)(asrc + 8);
    const u16* bsrc = wot + (size_t)(n0 + srow) * 64 + scol;
    *(uint4*)&Bs[srow][scol] = *(const uint4*)(bsrc);
    *(uint4*)&Bs[srow][scol + 8] = *(const uint4*)(bsrc + 8);
  }
  __syncthreads();
  bf16x8 a0 = *(const bf16x8*)&As[w * 16 + c16][g * 8];
  bf16x8 a1 = *(const bf16x8*)&As[w * 16 + c16][32 + g * 8];
  f32x4 acc[4] = {};
#pragma unroll
  for (int nt = 0; nt < 4; ++nt) {
    bf16x8 b0 = *(const bf16x8*)&Bs[nt * 16 + c16][g * 8];
    bf16x8 b1 = *(const bf16x8*)&Bs[nt * 16 + c16][32 + g * 8];
    acc[nt] = MFMA32(a0, b0, acc[nt]);
    acc[nt] = MFMA32(a1, b1, acc[nt]);
  }
#pragma unroll
  for (int nt = 0; nt < 4; ++nt)
#pragma unroll
    for (int j = 0; j < 4; ++j)
      __builtin_nontemporal_store(
          acc[nt][j],
          out + (size_t)(m0 + w * 16 + g * 4 + j) * 512 + n0 + nt * 16 + c16);
}

// ---------------------------------------------------------------------------
extern "C" void kernel_launch(void* const* d_in, const int* in_sizes, int n_in,
                              void* d_out, int out_size, void* d_ws,
                              size_t ws_size, hipStream_t stream) {
  (void)in_sizes; (void)n_in; (void)out_size; (void)ws_size;
  const float* x = (const float*)d_in[0];
  const float* wqkv = (const float*)d_in[1];
  const float* wout = (const float*)d_in[2];
  float* out = (float*)d_out;
  float* P = out + 4194304;  // attn_prob: 4*8*2048*2048 fp32

  u16* xh = (u16*)d_ws;                 // 4,194,304 (dead after qkv_gemm)
  u16* wt = xh + 4194304;               // 557,056
  u16* wot = wt + 557056;               // 32,768
  u16* Qb = wot + 32768;                // 4,194,304
  u16* Kb = Qb + 4194304;               // 4,194,304
  u16* Vt = Kb + 4194304;               // 524,288
  float* Obuf = (float*)(Vt + 524288);  // 4,194,304 fp32
  u16* meanb = xh;                      // alias: xh dead by then

  hipLaunchKernelGGL(prep_kernel, dim3(6400), dim3(256), 0, stream,
                     x, wqkv, wout, xh, wt, wot);
  hipLaunchKernelGGL(qkv_gemm_kernel, dim3(17, 64), dim3(256), 0, stream,
                     xh, wt, Qb, Kb, Vt);
  hipLaunchKernelGGL(attn_kernel, dim3(1024), dim3(256), 0, stream,
                     Qb, Kb, Vt, P, Obuf);
  hipLaunchKernelGGL(mean_kernel, dim3(512), dim3(256), 0, stream,
                     Obuf, meanb);
  hipLaunchKernelGGL(out_gemm_kernel, dim3(8, 128), dim3(256), 0, stream,
                     meanb, wot, out);
}